// Round 1
// baseline (2784.816 us; speedup 1.0000x reference)
//
#include <hip/hip_runtime.h>
#include <stdint.h>

// ---------------------------------------------------------------------------
// RPN loss: IoU>0.7 matching + argmax fix + exact JAX threefry sampling
// (partitionable PRNG path) + smooth-L1 + BCE, all on device.
// Sampling reproduced via backward rank-selection instead of full sorts.
// ---------------------------------------------------------------------------

#define N_PRED   131072
#define NBOXK    64
#define NM_TOT   8388608u          // N_PRED * NBOXK
#define TCAP     65536
#define NBINS    8192
#define BINSHIFT 19                // key >> 19 -> 13-bit bin
#define SLOTCAP  3072
#define MAXSLOT  192
#define NPAD     4096

struct WS {
  uint32_t P, M, n_pos, n_neg;
  uint32_t R[2];                   // shuffle rounds per chain (0=pos,1=neg)
  uint32_t S[2];                   // sizes per chain
  uint32_t kcnt[2];                // target counts per chain
  uint32_t sub[2][3][2];           // per-round subkeys
  uint32_t nslots;
  uint32_t pad_[31];
  unsigned long long colBest[NBOXK];      // packed (iou_bits<<32)|~row
  unsigned long long maskWords[N_PRED];   // 64 mask bits per pred row
  uint32_t T[TCAP];                // sorted flat positions of mask==true
  uint32_t tgt[2][256];            // current target ranks / positions
  uint32_t hist[NBINS];
  uint32_t cum[NBINS + 1];
  int32_t  binslot[NBINS];
  int32_t  tslot[256];
  uint32_t tlocal[256];
  uint32_t slotCnt[MAXSLOT];
  unsigned long long slotBuf[MAXSLOT][SLOTCAP];
};

// Threefry-2x32-20, matches JAX reference implementation exactly.
__device__ __forceinline__ void tf2(uint32_t k0, uint32_t k1,
                                    uint32_t& x0, uint32_t& x1) {
  uint32_t ks0 = k0, ks1 = k1, ks2 = k0 ^ k1 ^ 0x1BD11BDAu;
  uint32_t ks[3] = {ks0, ks1, ks2};
  const uint32_t R0[4] = {13u, 15u, 26u, 6u};
  const uint32_t R1[4] = {17u, 29u, 16u, 24u};
  x0 += ks[0]; x1 += ks[1];
#pragma unroll
  for (int i = 0; i < 5; ++i) {
    const uint32_t* rr = (i & 1) ? R1 : R0;
#pragma unroll
    for (int j = 0; j < 4; ++j) {
      x0 += x1;
      x1 = (x1 << rr[j]) | (x1 >> (32u - rr[j]));
      x1 ^= x0;
    }
    x0 += ks[(i + 1) % 3];
    x1 += ks[(i + 2) % 3] + (uint32_t)(i + 1);
  }
}

// partitionable random_bits for 32-bit: xor of the two outputs, counter = pos
__device__ __forceinline__ uint32_t tf_bits(uint32_t k0, uint32_t k1, uint32_t p) {
  uint32_t a = 0u, b = p;
  tf2(k0, k1, a, b);
  return a ^ b;
}

__global__ void k_init(WS* ws) {
  int t = threadIdx.x;
  if (t < NBOXK) ws->colBest[t] = 0ull;
}

// IoU mask + per-column packed argmax. Bit-exact f32 (no FMA contraction).
__global__ __launch_bounds__(256) void k_iou(const float4* __restrict__ pred,
                                             const float4* __restrict__ tgtb,
                                             WS* ws) {
  __shared__ float4 tb[NBOXK];
  __shared__ float ta[NBOXK];
  __shared__ unsigned long long cb[NBOXK];
  int tid = threadIdx.x;
  if (tid < NBOXK) {
    float4 b = tgtb[tid];
    tb[tid] = b;
    ta[tid] = __fmul_rn(__fsub_rn(b.z, b.x), __fsub_rn(b.w, b.y));
    cb[tid] = 0ull;
  }
  __syncthreads();
  int i = blockIdx.x * blockDim.x + tid;
  float4 p = pred[i];
  float pa = __fmul_rn(__fsub_rn(p.z, p.x), __fsub_rn(p.w, p.y));
  unsigned long long word = 0ull;
#pragma unroll 4
  for (int c = 0; c < NBOXK; ++c) {
    float4 t = tb[c];
    float ltx = fmaxf(p.x, t.x), lty = fmaxf(p.y, t.y);
    float rbx = fminf(p.z, t.z), rby = fminf(p.w, t.w);
    float wx = fmaxf(__fsub_rn(rbx, ltx), 0.0f);
    float wy = fmaxf(__fsub_rn(rby, lty), 0.0f);
    float inter = __fmul_rn(wx, wy);
    float uni = __fsub_rn(__fadd_rn(pa, ta[c]), inter);
    float iou = __fdiv_rn(inter, uni);
    if (iou > 0.7f) word |= (1ull << c);
    unsigned long long pk =
        ((unsigned long long)__float_as_uint(iou) << 32) |
        (unsigned long long)(~(uint32_t)i);
    atomicMax(&cb[c], pk);
  }
  ws->maskWords[i] = word;
  __syncthreads();
  if (tid < NBOXK) atomicMax(&ws->colBest[tid], cb[tid]);
}

// need[c] = column max <= 0.7 -> set bit at first-argmax row
__global__ void k_fix(WS* ws) {
  int c = threadIdx.x;
  if (c < NBOXK) {
    unsigned long long pk = ws->colBest[c];
    float best = __uint_as_float((uint32_t)(pk >> 32));
    if (!(best > 0.7f)) {
      uint32_t row = ~(uint32_t)(pk & 0xFFFFFFFFu);
      atomicOr(&ws->maskWords[row], 1ull << c);
    }
  }
}

// Ordered collect of true positions + all scalar/PRNG setup.
__global__ __launch_bounds__(1024) void k_collect(WS* ws) {
  __shared__ uint32_t part[1024];
  int t = threadIdx.x;
  const int ROWS = N_PRED / 1024;  // 128
  uint32_t base = (uint32_t)t * ROWS;
  uint32_t c = 0;
  for (int r = 0; r < ROWS; ++r)
    c += (uint32_t)__popcll(ws->maskWords[base + r]);
  part[t] = c;
  __syncthreads();
  for (int off = 1; off < 1024; off <<= 1) {
    uint32_t add = (t >= off) ? part[t - off] : 0u;
    __syncthreads();
    part[t] += add;
    __syncthreads();
  }
  uint32_t off0 = part[t] - c;
  uint32_t total = part[1023];
  for (int r = 0; r < ROWS; ++r) {
    unsigned long long w = ws->maskWords[base + r];
    while (w) {
      int bit = __ffsll((long long)w) - 1;
      w &= (w - 1);
      if (off0 < TCAP) ws->T[off0] = ((base + r) << 6) | (uint32_t)bit;
      off0++;
    }
  }
  if (t < 256) { ws->tgt[0][t] = (uint32_t)t; ws->tgt[1][t] = (uint32_t)t; }
  if (t == 0) {
    uint32_t P = total < (uint32_t)TCAP ? total : (uint32_t)TCAP;
    uint32_t M = NM_TOT - P;
    uint32_t npos = P < 128u ? P : 128u;
    ws->P = P; ws->M = M;
    ws->n_pos = npos; ws->n_neg = 256u - npos;
    ws->S[0] = P; ws->S[1] = M;
    ws->kcnt[0] = npos; ws->kcnt[1] = 256u - npos;
    const double LOGU = 22.18070977791825;  // log(2^32 - 1)
    for (int d = 0; d < 2; ++d) {
      uint32_t Sd = ws->S[d];
      int R = 0;
      if (Sd > 1u) {
        R = (int)ceil(3.0 * log((double)Sd) / LOGU);
        if (R < 1) R = 1;
        if (R > 3) R = 3;
      }
      ws->R[d] = (uint32_t)R;
      // fold_in(key(42), d) = TF(key, 0, d)
      uint32_t ck0, ck1;
      { uint32_t a = 0u, b = (uint32_t)d; tf2(0u, 42u, a, b); ck0 = a; ck1 = b; }
      // split (partitionable/foldlike): newkey = TF(k,0,0), subkey = TF(k,0,1)
      for (int rr = 0; rr < 3; ++rr) {
        uint32_t s0 = 0u, s1 = 1u; tf2(ck0, ck1, s0, s1);
        ws->sub[d][rr][0] = s0; ws->sub[d][rr][1] = s1;
        uint32_t n0 = 0u, n1 = 0u; tf2(ck0, ck1, n0, n1);
        ck0 = n0; ck1 = n1;
      }
    }
  }
}

__global__ void k_passclear(WS* ws) {
  int g = blockIdx.x * blockDim.x + threadIdx.x;
  if (g < NBINS) { ws->hist[g] = 0u; ws->binslot[g] = -1; }
  if (g < MAXSLOT) ws->slotCnt[g] = 0u;
  if (g == 0) ws->nslots = 0u;
}

__global__ __launch_bounds__(256) void k_hist(WS* ws, int d, int m) {
  int r = (int)ws->R[d] - m;
  if (r < 1) return;
  __shared__ uint32_t lh[NBINS];
  for (int i = threadIdx.x; i < NBINS; i += 256) lh[i] = 0u;
  __syncthreads();
  uint32_t S = ws->S[d];
  uint32_t sk0 = ws->sub[d][r - 1][0], sk1 = ws->sub[d][r - 1][1];
  uint32_t stride = gridDim.x * blockDim.x;
  for (uint32_t j = blockIdx.x * blockDim.x + threadIdx.x; j < S; j += stride) {
    uint32_t kk = tf_bits(sk0, sk1, j);
    atomicAdd(&lh[kk >> BINSHIFT], 1u);
  }
  __syncthreads();
  for (int i = threadIdx.x; i < NBINS; i += 256) {
    uint32_t v = lh[i];
    if (v) atomicAdd(&ws->hist[i], v);
  }
}

__global__ __launch_bounds__(1024) void k_scanloc(WS* ws, int d, int m) {
  int r = (int)ws->R[d] - m;
  if (r < 1) return;
  __shared__ uint32_t part[1024];
  int t = threadIdx.x;
  const int E = NBINS / 1024;  // 8
  uint32_t lv[E];
  uint32_t s = 0;
  uint32_t base = (uint32_t)t * E;
  for (int e = 0; e < E; ++e) { lv[e] = ws->hist[base + e]; s += lv[e]; }
  part[t] = s;
  __syncthreads();
  for (int off = 1; off < 1024; off <<= 1) {
    uint32_t add = (t >= off) ? part[t - off] : 0u;
    __syncthreads();
    part[t] += add;
    __syncthreads();
  }
  uint32_t run = part[t] - s;
  for (int e = 0; e < E; ++e) { ws->cum[base + e] = run; run += lv[e]; }
  if (t == 1023) ws->cum[NBINS] = run;
  __syncthreads();
  if (t == 0) {
    uint32_t k = ws->kcnt[d];
    uint32_t ns = 0;
    for (uint32_t sId = 0; sId < k; ++sId) {
      uint32_t tr = ws->tgt[d][sId];
      uint32_t lo = 0, hi = NBINS;  // cum[lo] <= tr < cum[hi]
      while (hi - lo > 1u) {
        uint32_t mid = (lo + hi) >> 1;
        if (ws->cum[mid] <= tr) lo = mid; else hi = mid;
      }
      int slot = ws->binslot[lo];
      if (slot < 0) { slot = (int)ns++; ws->binslot[lo] = slot; }
      ws->tslot[sId] = slot;
      ws->tlocal[sId] = tr - ws->cum[lo];
    }
    ws->nslots = ns;
  }
}

__global__ __launch_bounds__(256) void k_gather(WS* ws, int d, int m) {
  int r = (int)ws->R[d] - m;
  if (r < 1) return;
  uint32_t S = ws->S[d];
  uint32_t sk0 = ws->sub[d][r - 1][0], sk1 = ws->sub[d][r - 1][1];
  uint32_t stride = gridDim.x * blockDim.x;
  for (uint32_t j = blockIdx.x * blockDim.x + threadIdx.x; j < S; j += stride) {
    uint32_t kk = tf_bits(sk0, sk1, j);
    int sl = ws->binslot[kk >> BINSHIFT];
    if (sl >= 0) {
      uint32_t idx = atomicAdd(&ws->slotCnt[sl], 1u);
      if (idx < SLOTCAP)
        ws->slotBuf[sl][idx] =
            ((unsigned long long)kk << 24) | (unsigned long long)j;
    }
  }
}

// Sort one needed bin in LDS (packed (key,pos) => exact stable order),
// pick the elements whose local rank matches each target in this bin.
__global__ __launch_bounds__(256) void k_bsort(WS* ws, int d, int m) {
  int r = (int)ws->R[d] - m;
  if (r < 1) return;
  int slot = blockIdx.x;
  if (slot >= (int)ws->nslots) return;
  __shared__ unsigned long long sh[NPAD];
  uint32_t cnt = ws->slotCnt[slot];
  if (cnt > SLOTCAP) cnt = SLOTCAP;
  for (int i = threadIdx.x; i < NPAD; i += 256)
    sh[i] = (i < (int)cnt) ? ws->slotBuf[slot][i] : ~0ull;
  __syncthreads();
  for (int ksz = 2; ksz <= NPAD; ksz <<= 1) {
    for (int jsz = ksz >> 1; jsz > 0; jsz >>= 1) {
      for (int i = threadIdx.x; i < NPAD; i += 256) {
        int p = i ^ jsz;
        if (p > i) {
          unsigned long long a = sh[i], b = sh[p];
          bool up = ((i & ksz) == 0);
          if (up ? (a > b) : (a < b)) { sh[i] = b; sh[p] = a; }
        }
      }
      __syncthreads();
    }
  }
  uint32_t k = ws->kcnt[d];
  for (uint32_t sId = threadIdx.x; sId < k; sId += 256) {
    if (ws->tslot[sId] == slot) {
      unsigned long long v = sh[ws->tlocal[sId]];
      ws->tgt[d][sId] = (uint32_t)(v & 0xFFFFFFull);
    }
  }
}

__device__ __forceinline__ float sl1(float dd) {
  float ad = fabsf(dd);
  return (ad < 1.0f) ? 0.5f * dd * dd : ad - 0.5f;
}

__global__ __launch_bounds__(256) void k_loss(WS* ws,
                                              const float* __restrict__ reg,
                                              const float* __restrict__ obj,
                                              const float4* __restrict__ tgtb,
                                              const float4* __restrict__ anch,
                                              float* out) {
  int s = threadIdx.x;
  uint32_t npos = ws->n_pos;
  double lr = 0.0, bc = 0.0;
  if (s < (int)npos) {
    uint32_t v = ws->tgt[0][s];
    uint32_t pa = ws->T[v];
    uint32_t i = pa >> 6, j = pa & 63u;
    float4 t = tgtb[j];
    float tcx = (t.x + t.z) * 0.5f, tcy = (t.y + t.w) * 0.5f;
    float tw = t.z - t.x, th = t.w - t.y;
    float4 a = anch[i];
    float r0 = (tcx - a.x) / a.z;
    float r1 = (tcy - a.y) / a.w;
    float r2 = logf(tw / a.z);
    float r3 = logf(th / a.w);
    lr = (double)sl1(reg[i * 4 + 0] - r0) + (double)sl1(reg[i * 4 + 1] - r1) +
         (double)sl1(reg[i * 4 + 2] - r2) + (double)sl1(reg[i * 4 + 3] - r3);
    float x = obj[i];
    bc = (double)(fmaxf(x, 0.0f) - x + log1pf(expf(-fabsf(x))));
  } else {
    uint32_t e = ws->tgt[1][s - (int)npos];
    uint32_t f = e;
    uint32_t P = ws->P;
    for (uint32_t q = 0; q < P; ++q) {
      if (ws->T[q] <= f) f++; else break;
    }
    uint32_t i = f >> 6;
    float x = obj[i];
    bc = (double)(fmaxf(x, 0.0f) + log1pf(expf(-fabsf(x))));
  }
  __shared__ double sA[256], sB[256];
  sA[s] = lr; sB[s] = bc;
  __syncthreads();
  for (int off = 128; off > 0; off >>= 1) {
    if (s < off) { sA[s] += sA[s + off]; sB[s] += sB[s + off]; }
    __syncthreads();
  }
  if (s == 0)
    out[0] = (float)(sA[0] * (10.0 / 2500.0) + sB[0] * (1.0 / 256.0));
}

extern "C" void kernel_launch(void* const* d_in, const int* in_sizes, int n_in,
                              void* d_out, int out_size, void* d_ws,
                              size_t ws_size, hipStream_t stream) {
  const float*  reg  = (const float*)d_in[0];
  const float*  obj  = (const float*)d_in[1];
  const float4* pred = (const float4*)d_in[2];
  const float4* tgtb = (const float4*)d_in[3];
  const float4* anch = (const float4*)d_in[4];
  float* out = (float*)d_out;
  WS* ws = (WS*)d_ws;
  (void)in_sizes; (void)n_in; (void)out_size; (void)ws_size;

  k_init<<<1, 64, 0, stream>>>(ws);
  k_iou<<<N_PRED / 256, 256, 0, stream>>>(pred, tgtb, ws);
  k_fix<<<1, 64, 0, stream>>>(ws);
  k_collect<<<1, 1024, 0, stream>>>(ws);
  for (int d = 0; d < 2; ++d) {
    for (int m = 0; m < 3; ++m) {
      k_passclear<<<(NBINS + 255) / 256, 256, 0, stream>>>(ws);
      k_hist<<<128, 256, 0, stream>>>(ws, d, m);
      k_scanloc<<<1, 1024, 0, stream>>>(ws, d, m);
      k_gather<<<256, 256, 0, stream>>>(ws, d, m);
      k_bsort<<<MAXSLOT, 256, 0, stream>>>(ws, d, m);
    }
  }
  k_loss<<<1, 256, 0, stream>>>(ws, reg, obj, tgtb, anch, out);
}

// Round 2
// 1408.462 us; speedup vs baseline: 1.9772x; 1.9772x over previous
//
#include <hip/hip_runtime.h>
#include <stdint.h>

// ---------------------------------------------------------------------------
// RPN loss: IoU>0.7 matching + argmax fix + exact JAX threefry sampling
// (partitionable PRNG path) + smooth-L1 + BCE, all on device.
// Sampling reproduced via backward rank-selection instead of full sorts.
// R1: k_scanloc serial tail (dependent global-latency bound, 320us/launch)
//     replaced by LDS-resident cum + parallel binary search + CAS slot dedup.
//     k_bsort now sorts next_pow2(cnt) instead of fixed 4096.
// ---------------------------------------------------------------------------

#define N_PRED   131072
#define NBOXK    64
#define NM_TOT   8388608u          // N_PRED * NBOXK
#define TCAP     65536
#define NBINS    8192
#define BINSHIFT 19                // key >> 19 -> 13-bit bin
#define SLOTCAP  3072
#define MAXSLOT  192
#define NPAD     4096

struct WS {
  uint32_t P, M, n_pos, n_neg;
  uint32_t R[2];                   // shuffle rounds per chain (0=pos,1=neg)
  uint32_t S[2];                   // sizes per chain
  uint32_t kcnt[2];                // target counts per chain
  uint32_t sub[2][3][2];           // per-round subkeys
  uint32_t nslots;
  uint32_t pad_[31];
  unsigned long long colBest[NBOXK];      // packed (iou_bits<<32)|~row
  unsigned long long maskWords[N_PRED];   // 64 mask bits per pred row
  uint32_t T[TCAP];                // sorted flat positions of mask==true
  uint32_t tgt[2][256];            // current target ranks / positions
  uint32_t hist[NBINS];
  int32_t  binslot[NBINS];
  int32_t  tslot[256];
  uint32_t tlocal[256];
  uint32_t slotCnt[MAXSLOT];
  unsigned long long slotBuf[MAXSLOT][SLOTCAP];
};

// Threefry-2x32-20, matches JAX reference implementation exactly.
__device__ __forceinline__ void tf2(uint32_t k0, uint32_t k1,
                                    uint32_t& x0, uint32_t& x1) {
  uint32_t ks[3] = {k0, k1, k0 ^ k1 ^ 0x1BD11BDAu};
  const uint32_t R0[4] = {13u, 15u, 26u, 6u};
  const uint32_t R1[4] = {17u, 29u, 16u, 24u};
  x0 += ks[0]; x1 += ks[1];
#pragma unroll
  for (int i = 0; i < 5; ++i) {
    const uint32_t* rr = (i & 1) ? R1 : R0;
#pragma unroll
    for (int j = 0; j < 4; ++j) {
      x0 += x1;
      x1 = (x1 << rr[j]) | (x1 >> (32u - rr[j]));
      x1 ^= x0;
    }
    x0 += ks[(i + 1) % 3];
    x1 += ks[(i + 2) % 3] + (uint32_t)(i + 1);
  }
}

// partitionable random_bits for 32-bit: xor of the two outputs, counter = pos
__device__ __forceinline__ uint32_t tf_bits(uint32_t k0, uint32_t k1, uint32_t p) {
  uint32_t a = 0u, b = p;
  tf2(k0, k1, a, b);
  return a ^ b;
}

__global__ void k_init(WS* ws) {
  int t = threadIdx.x;
  if (t < NBOXK) ws->colBest[t] = 0ull;
}

// IoU mask + per-column packed argmax. Bit-exact f32 (no FMA contraction).
__global__ __launch_bounds__(256) void k_iou(const float4* __restrict__ pred,
                                             const float4* __restrict__ tgtb,
                                             WS* ws) {
  __shared__ float4 tb[NBOXK];
  __shared__ float ta[NBOXK];
  __shared__ unsigned long long cb[NBOXK];
  int tid = threadIdx.x;
  if (tid < NBOXK) {
    float4 b = tgtb[tid];
    tb[tid] = b;
    ta[tid] = __fmul_rn(__fsub_rn(b.z, b.x), __fsub_rn(b.w, b.y));
    cb[tid] = 0ull;
  }
  __syncthreads();
  int i = blockIdx.x * blockDim.x + tid;
  float4 p = pred[i];
  float pa = __fmul_rn(__fsub_rn(p.z, p.x), __fsub_rn(p.w, p.y));
  unsigned long long word = 0ull;
#pragma unroll 4
  for (int c = 0; c < NBOXK; ++c) {
    float4 t = tb[c];
    float ltx = fmaxf(p.x, t.x), lty = fmaxf(p.y, t.y);
    float rbx = fminf(p.z, t.z), rby = fminf(p.w, t.w);
    float wx = fmaxf(__fsub_rn(rbx, ltx), 0.0f);
    float wy = fmaxf(__fsub_rn(rby, lty), 0.0f);
    float inter = __fmul_rn(wx, wy);
    float uni = __fsub_rn(__fadd_rn(pa, ta[c]), inter);
    float iou = __fdiv_rn(inter, uni);
    if (iou > 0.7f) word |= (1ull << c);
    unsigned long long pk =
        ((unsigned long long)__float_as_uint(iou) << 32) |
        (unsigned long long)(~(uint32_t)i);
    atomicMax(&cb[c], pk);
  }
  ws->maskWords[i] = word;
  __syncthreads();
  if (tid < NBOXK) atomicMax(&ws->colBest[tid], cb[tid]);
}

// need[c] = column max <= 0.7 -> set bit at first-argmax row
__global__ void k_fix(WS* ws) {
  int c = threadIdx.x;
  if (c < NBOXK) {
    unsigned long long pk = ws->colBest[c];
    float best = __uint_as_float((uint32_t)(pk >> 32));
    if (!(best > 0.7f)) {
      uint32_t row = ~(uint32_t)(pk & 0xFFFFFFFFu);
      atomicOr(&ws->maskWords[row], 1ull << c);
    }
  }
}

// Ordered collect of true positions + all scalar/PRNG setup.
__global__ __launch_bounds__(1024) void k_collect(WS* ws) {
  __shared__ uint32_t part[1024];
  int t = threadIdx.x;
  const int ROWS = N_PRED / 1024;  // 128
  uint32_t base = (uint32_t)t * ROWS;
  uint32_t c = 0;
  for (int r = 0; r < ROWS; ++r)
    c += (uint32_t)__popcll(ws->maskWords[base + r]);
  part[t] = c;
  __syncthreads();
  for (int off = 1; off < 1024; off <<= 1) {
    uint32_t add = (t >= off) ? part[t - off] : 0u;
    __syncthreads();
    part[t] += add;
    __syncthreads();
  }
  uint32_t off0 = part[t] - c;
  uint32_t total = part[1023];
  for (int r = 0; r < ROWS; ++r) {
    unsigned long long w = ws->maskWords[base + r];
    while (w) {
      int bit = __ffsll((long long)w) - 1;
      w &= (w - 1);
      if (off0 < TCAP) ws->T[off0] = ((base + r) << 6) | (uint32_t)bit;
      off0++;
    }
  }
  if (t < 256) { ws->tgt[0][t] = (uint32_t)t; ws->tgt[1][t] = (uint32_t)t; }
  if (t == 0) {
    uint32_t P = total < (uint32_t)TCAP ? total : (uint32_t)TCAP;
    uint32_t M = NM_TOT - P;
    uint32_t npos = P < 128u ? P : 128u;
    ws->P = P; ws->M = M;
    ws->n_pos = npos; ws->n_neg = 256u - npos;
    ws->S[0] = P; ws->S[1] = M;
    ws->kcnt[0] = npos; ws->kcnt[1] = 256u - npos;
    const double LOGU = 22.18070977791825;  // log(2^32 - 1)
    for (int d = 0; d < 2; ++d) {
      uint32_t Sd = ws->S[d];
      int R = 0;
      if (Sd > 1u) {
        R = (int)ceil(3.0 * log((double)Sd) / LOGU);
        if (R < 1) R = 1;
        if (R > 3) R = 3;
      }
      ws->R[d] = (uint32_t)R;
      // fold_in(key(42), d) = TF(key, 0, d)
      uint32_t ck0, ck1;
      { uint32_t a = 0u, b = (uint32_t)d; tf2(0u, 42u, a, b); ck0 = a; ck1 = b; }
      // split (partitionable/foldlike): newkey = TF(k,0,0), subkey = TF(k,0,1)
      for (int rr = 0; rr < 3; ++rr) {
        uint32_t s0 = 0u, s1 = 1u; tf2(ck0, ck1, s0, s1);
        ws->sub[d][rr][0] = s0; ws->sub[d][rr][1] = s1;
        uint32_t n0 = 0u, n1 = 0u; tf2(ck0, ck1, n0, n1);
        ck0 = n0; ck1 = n1;
      }
    }
  }
}

__global__ void k_passclear(WS* ws) {
  int g = blockIdx.x * blockDim.x + threadIdx.x;
  if (g < NBINS) { ws->hist[g] = 0u; ws->binslot[g] = -1; }
  if (g < MAXSLOT) ws->slotCnt[g] = 0u;
  if (g == 0) ws->nslots = 0u;
}

__global__ __launch_bounds__(256) void k_hist(WS* ws, int d, int m) {
  int r = (int)ws->R[d] - m;
  if (r < 1) return;
  __shared__ uint32_t lh[NBINS];
  for (int i = threadIdx.x; i < NBINS; i += 256) lh[i] = 0u;
  __syncthreads();
  uint32_t S = ws->S[d];
  uint32_t sk0 = ws->sub[d][r - 1][0], sk1 = ws->sub[d][r - 1][1];
  uint32_t stride = gridDim.x * blockDim.x;
  for (uint32_t j = blockIdx.x * blockDim.x + threadIdx.x; j < S; j += stride) {
    uint32_t kk = tf_bits(sk0, sk1, j);
    atomicAdd(&lh[kk >> BINSHIFT], 1u);
  }
  __syncthreads();
  for (int i = threadIdx.x; i < NBINS; i += 256) {
    uint32_t v = lh[i];
    if (v) atomicAdd(&ws->hist[i], v);
  }
}

// Scan hist in LDS; parallel per-target binary search; CAS-based slot dedup.
// cum never touches global memory (was: 320us serial dependent-load tail).
__global__ __launch_bounds__(1024) void k_scanloc(WS* ws, int d, int m) {
  int r = (int)ws->R[d] - m;
  if (r < 1) return;
  __shared__ uint32_t cumS[NBINS + 1];
  __shared__ uint32_t part[1024];
  int t = threadIdx.x;
  const int E = NBINS / 1024;  // 8
  uint32_t lv[E];
  uint32_t s = 0;
  uint32_t base = (uint32_t)t * E;
#pragma unroll
  for (int e = 0; e < E; ++e) { lv[e] = ws->hist[base + e]; s += lv[e]; }
  part[t] = s;
  __syncthreads();
  for (int off = 1; off < 1024; off <<= 1) {
    uint32_t add = (t >= off) ? part[t - off] : 0u;
    __syncthreads();
    part[t] += add;
    __syncthreads();
  }
  uint32_t run = part[t] - s;
#pragma unroll
  for (int e = 0; e < E; ++e) { cumS[base + e] = run; run += lv[e]; }
  if (t == 1023) cumS[NBINS] = run;
  __syncthreads();

  uint32_t k = ws->kcnt[d];
  uint32_t lo = 0;
  int old = 0;
  if (t < (int)k) {
    uint32_t tr = ws->tgt[d][t];
    uint32_t hi = NBINS;  // invariant: cumS[lo] <= tr < cumS[hi]
    while (hi - lo > 1u) {
      uint32_t mid = (lo + hi) >> 1;
      if (cumS[mid] <= tr) lo = mid; else hi = mid;
    }
    ws->tlocal[t] = tr - cumS[lo];
    // phase 1: claim the bin (marker = 0x10000+t, never collides with slot id)
    old = atomicCAS(&ws->binslot[lo], -1, (int)(0x10000u + (uint32_t)t));
  }
  __syncthreads();
  // phase 2: winners allocate dense slot ids and overwrite the marker
  if (t < (int)k && old == -1) {
    uint32_t slot = atomicAdd(&ws->nslots, 1u);
    ws->binslot[lo] = (int)slot;   // plain atomic-width store; CAS can't hit (-1 gone)
  }
  __syncthreads();
  // phase 3: everyone reads the final slot id
  if (t < (int)k) ws->tslot[t] = ws->binslot[lo];
}

__global__ __launch_bounds__(256) void k_gather(WS* ws, int d, int m) {
  int r = (int)ws->R[d] - m;
  if (r < 1) return;
  uint32_t S = ws->S[d];
  uint32_t sk0 = ws->sub[d][r - 1][0], sk1 = ws->sub[d][r - 1][1];
  uint32_t stride = gridDim.x * blockDim.x;
  for (uint32_t j = blockIdx.x * blockDim.x + threadIdx.x; j < S; j += stride) {
    uint32_t kk = tf_bits(sk0, sk1, j);
    int sl = ws->binslot[kk >> BINSHIFT];
    if (sl >= 0) {
      uint32_t idx = atomicAdd(&ws->slotCnt[sl], 1u);
      if (idx < SLOTCAP)
        ws->slotBuf[sl][idx] =
            ((unsigned long long)kk << 24) | (unsigned long long)j;
    }
  }
}

// Sort one needed bin in LDS (packed (key,pos) => exact stable order),
// pick the elements whose local rank matches each target in this bin.
// Sort size = next_pow2(cnt), not fixed NPAD.
__global__ __launch_bounds__(256) void k_bsort(WS* ws, int d, int m) {
  int r = (int)ws->R[d] - m;
  if (r < 1) return;
  int slot = blockIdx.x;
  if (slot >= (int)ws->nslots) return;
  __shared__ unsigned long long sh[NPAD];
  uint32_t cnt = ws->slotCnt[slot];
  if (cnt > SLOTCAP) cnt = SLOTCAP;
  int n2 = 256;
  while (n2 < (int)cnt) n2 <<= 1;  // <= 4096
  for (int i = threadIdx.x; i < n2; i += 256)
    sh[i] = (i < (int)cnt) ? ws->slotBuf[slot][i] : ~0ull;
  __syncthreads();
  for (int ksz = 2; ksz <= n2; ksz <<= 1) {
    for (int jsz = ksz >> 1; jsz > 0; jsz >>= 1) {
      for (int i = threadIdx.x; i < n2; i += 256) {
        int p = i ^ jsz;
        if (p > i) {
          unsigned long long a = sh[i], b = sh[p];
          bool up = ((i & ksz) == 0);
          if (up ? (a > b) : (a < b)) { sh[i] = b; sh[p] = a; }
        }
      }
      __syncthreads();
    }
  }
  uint32_t k = ws->kcnt[d];
  for (uint32_t sId = threadIdx.x; sId < k; sId += 256) {
    if (ws->tslot[sId] == slot) {
      unsigned long long v = sh[ws->tlocal[sId]];
      ws->tgt[d][sId] = (uint32_t)(v & 0xFFFFFFull);
    }
  }
}

__device__ __forceinline__ float sl1(float dd) {
  float ad = fabsf(dd);
  return (ad < 1.0f) ? 0.5f * dd * dd : ad - 0.5f;
}

__global__ __launch_bounds__(256) void k_loss(WS* ws,
                                              const float* __restrict__ reg,
                                              const float* __restrict__ obj,
                                              const float4* __restrict__ tgtb,
                                              const float4* __restrict__ anch,
                                              float* out) {
  int s = threadIdx.x;
  uint32_t npos = ws->n_pos;
  double lr = 0.0, bc = 0.0;
  if (s < (int)npos) {
    uint32_t v = ws->tgt[0][s];
    uint32_t pa = ws->T[v];
    uint32_t i = pa >> 6, j = pa & 63u;
    float4 t = tgtb[j];
    float tcx = (t.x + t.z) * 0.5f, tcy = (t.y + t.w) * 0.5f;
    float tw = t.z - t.x, th = t.w - t.y;
    float4 a = anch[i];
    float r0 = (tcx - a.x) / a.z;
    float r1 = (tcy - a.y) / a.w;
    float r2 = logf(tw / a.z);
    float r3 = logf(th / a.w);
    lr = (double)sl1(reg[i * 4 + 0] - r0) + (double)sl1(reg[i * 4 + 1] - r1) +
         (double)sl1(reg[i * 4 + 2] - r2) + (double)sl1(reg[i * 4 + 3] - r3);
    float x = obj[i];
    bc = (double)(fmaxf(x, 0.0f) - x + log1pf(expf(-fabsf(x))));
  } else {
    uint32_t e = ws->tgt[1][s - (int)npos];
    uint32_t f = e;
    uint32_t P = ws->P;
    for (uint32_t q = 0; q < P; ++q) {
      if (ws->T[q] <= f) f++; else break;
    }
    uint32_t i = f >> 6;
    float x = obj[i];
    bc = (double)(fmaxf(x, 0.0f) + log1pf(expf(-fabsf(x))));
  }
  __shared__ double sA[256], sB[256];
  sA[s] = lr; sB[s] = bc;
  __syncthreads();
  for (int off = 128; off > 0; off >>= 1) {
    if (s < off) { sA[s] += sA[s + off]; sB[s] += sB[s + off]; }
    __syncthreads();
  }
  if (s == 0)
    out[0] = (float)(sA[0] * (10.0 / 2500.0) + sB[0] * (1.0 / 256.0));
}

extern "C" void kernel_launch(void* const* d_in, const int* in_sizes, int n_in,
                              void* d_out, int out_size, void* d_ws,
                              size_t ws_size, hipStream_t stream) {
  const float*  reg  = (const float*)d_in[0];
  const float*  obj  = (const float*)d_in[1];
  const float4* pred = (const float4*)d_in[2];
  const float4* tgtb = (const float4*)d_in[3];
  const float4* anch = (const float4*)d_in[4];
  float* out = (float*)d_out;
  WS* ws = (WS*)d_ws;
  (void)in_sizes; (void)n_in; (void)out_size; (void)ws_size;

  k_init<<<1, 64, 0, stream>>>(ws);
  k_iou<<<N_PRED / 256, 256, 0, stream>>>(pred, tgtb, ws);
  k_fix<<<1, 64, 0, stream>>>(ws);
  k_collect<<<1, 1024, 0, stream>>>(ws);
  for (int d = 0; d < 2; ++d) {
    for (int m = 0; m < 3; ++m) {
      k_passclear<<<(NBINS + 255) / 256, 256, 0, stream>>>(ws);
      k_hist<<<128, 256, 0, stream>>>(ws, d, m);
      k_scanloc<<<1, 1024, 0, stream>>>(ws, d, m);
      k_gather<<<256, 256, 0, stream>>>(ws, d, m);
      k_bsort<<<MAXSLOT, 256, 0, stream>>>(ws, d, m);
    }
  }
  k_loss<<<1, 256, 0, stream>>>(ws, reg, obj, tgtb, anch, out);
}

// Round 3
// 770.000 us; speedup vs baseline: 3.6166x; 1.8292x over previous
//
#include <hip/hip_runtime.h>
#include <stdint.h>

// ---------------------------------------------------------------------------
// RPN loss: IoU>0.7 matching + argmax fix + exact JAX threefry sampling
// (partitionable PRNG path) + smooth-L1 + BCE, all on device.
// R1: k_scanloc serial tail -> LDS cum + parallel search (2785->1408us).
// R2: k_gather was latency-bound (VALUBusy 6.9%, occ 10%: dependent binslot
//     load + returning hot atomics, 305us x3). Now: binslot in LDS, LDS hit
//     buffer, per-block per-slot range reservation; 256x1024 launch.
//     k_hist widened to 256x1024 + unroll-2 (independent threefry chains).
// ---------------------------------------------------------------------------

#define N_PRED   131072
#define NBOXK    64
#define NM_TOT   8388608u          // N_PRED * NBOXK
#define TCAP     65536
#define NBINS    8192
#define BINSHIFT 19                // key >> 19 -> 13-bit bin
#define SLOTCAP  3072
#define MAXSLOT  192
#define NPAD     4096
#define HCAP     2048              // per-block LDS hit buffer (gather)

typedef unsigned long long ull;

struct WS {
  uint32_t P, M, n_pos, n_neg;
  uint32_t R[2];                   // shuffle rounds per chain (0=pos,1=neg)
  uint32_t S[2];                   // sizes per chain
  uint32_t kcnt[2];                // target counts per chain
  uint32_t sub[2][3][2];           // per-round subkeys
  uint32_t nslots;
  uint32_t pad_[31];
  ull      colBest[NBOXK];         // packed (iou_bits<<32)|~row
  ull      maskWords[N_PRED];      // 64 mask bits per pred row
  uint32_t T[TCAP];                // sorted flat positions of mask==true
  uint32_t tgt[2][256];            // current target ranks / positions
  uint32_t hist[NBINS];
  int32_t  binslot[NBINS];
  int32_t  tslot[256];
  uint32_t tlocal[256];
  uint32_t slotCnt[MAXSLOT];
  ull      slotBuf[MAXSLOT][SLOTCAP];
};

// Threefry-2x32-20, matches JAX reference implementation exactly.
__device__ __forceinline__ void tf2(uint32_t k0, uint32_t k1,
                                    uint32_t& x0, uint32_t& x1) {
  uint32_t ks[3] = {k0, k1, k0 ^ k1 ^ 0x1BD11BDAu};
  const uint32_t R0[4] = {13u, 15u, 26u, 6u};
  const uint32_t R1[4] = {17u, 29u, 16u, 24u};
  x0 += ks[0]; x1 += ks[1];
#pragma unroll
  for (int i = 0; i < 5; ++i) {
    const uint32_t* rr = (i & 1) ? R1 : R0;
#pragma unroll
    for (int j = 0; j < 4; ++j) {
      x0 += x1;
      x1 = (x1 << rr[j]) | (x1 >> (32u - rr[j]));
      x1 ^= x0;
    }
    x0 += ks[(i + 1) % 3];
    x1 += ks[(i + 2) % 3] + (uint32_t)(i + 1);
  }
}

// partitionable random_bits for 32-bit: xor of the two outputs, counter = pos
__device__ __forceinline__ uint32_t tf_bits(uint32_t k0, uint32_t k1, uint32_t p) {
  uint32_t a = 0u, b = p;
  tf2(k0, k1, a, b);
  return a ^ b;
}

__global__ void k_init(WS* ws) {
  int t = threadIdx.x;
  if (t < NBOXK) ws->colBest[t] = 0ull;
}

// IoU mask + per-column packed argmax. Bit-exact f32 (no FMA contraction).
__global__ __launch_bounds__(256) void k_iou(const float4* __restrict__ pred,
                                             const float4* __restrict__ tgtb,
                                             WS* ws) {
  __shared__ float4 tb[NBOXK];
  __shared__ float ta[NBOXK];
  __shared__ ull cb[NBOXK];
  int tid = threadIdx.x;
  if (tid < NBOXK) {
    float4 b = tgtb[tid];
    tb[tid] = b;
    ta[tid] = __fmul_rn(__fsub_rn(b.z, b.x), __fsub_rn(b.w, b.y));
    cb[tid] = 0ull;
  }
  __syncthreads();
  int i = blockIdx.x * blockDim.x + tid;
  float4 p = pred[i];
  float pa = __fmul_rn(__fsub_rn(p.z, p.x), __fsub_rn(p.w, p.y));
  ull word = 0ull;
#pragma unroll 4
  for (int c = 0; c < NBOXK; ++c) {
    float4 t = tb[c];
    float ltx = fmaxf(p.x, t.x), lty = fmaxf(p.y, t.y);
    float rbx = fminf(p.z, t.z), rby = fminf(p.w, t.w);
    float wx = fmaxf(__fsub_rn(rbx, ltx), 0.0f);
    float wy = fmaxf(__fsub_rn(rby, lty), 0.0f);
    float inter = __fmul_rn(wx, wy);
    float uni = __fsub_rn(__fadd_rn(pa, ta[c]), inter);
    float iou = __fdiv_rn(inter, uni);
    if (iou > 0.7f) word |= (1ull << c);
    ull pk = ((ull)__float_as_uint(iou) << 32) | (ull)(~(uint32_t)i);
    atomicMax(&cb[c], pk);
  }
  ws->maskWords[i] = word;
  __syncthreads();
  if (tid < NBOXK) atomicMax(&ws->colBest[tid], cb[tid]);
}

// need[c] = column max <= 0.7 -> set bit at first-argmax row
__global__ void k_fix(WS* ws) {
  int c = threadIdx.x;
  if (c < NBOXK) {
    ull pk = ws->colBest[c];
    float best = __uint_as_float((uint32_t)(pk >> 32));
    if (!(best > 0.7f)) {
      uint32_t row = ~(uint32_t)(pk & 0xFFFFFFFFu);
      atomicOr(&ws->maskWords[row], 1ull << c);
    }
  }
}

// Ordered collect of true positions + all scalar/PRNG setup.
__global__ __launch_bounds__(1024) void k_collect(WS* ws) {
  __shared__ uint32_t part[1024];
  int t = threadIdx.x;
  const int ROWS = N_PRED / 1024;  // 128
  uint32_t base = (uint32_t)t * ROWS;
  uint32_t c = 0;
  for (int r = 0; r < ROWS; ++r)
    c += (uint32_t)__popcll(ws->maskWords[base + r]);
  part[t] = c;
  __syncthreads();
  for (int off = 1; off < 1024; off <<= 1) {
    uint32_t add = (t >= off) ? part[t - off] : 0u;
    __syncthreads();
    part[t] += add;
    __syncthreads();
  }
  uint32_t off0 = part[t] - c;
  uint32_t total = part[1023];
  for (int r = 0; r < ROWS; ++r) {
    ull w = ws->maskWords[base + r];
    while (w) {
      int bit = __ffsll((long long)w) - 1;
      w &= (w - 1);
      if (off0 < TCAP) ws->T[off0] = ((base + r) << 6) | (uint32_t)bit;
      off0++;
    }
  }
  if (t < 256) { ws->tgt[0][t] = (uint32_t)t; ws->tgt[1][t] = (uint32_t)t; }
  if (t == 0) {
    uint32_t P = total < (uint32_t)TCAP ? total : (uint32_t)TCAP;
    uint32_t M = NM_TOT - P;
    uint32_t npos = P < 128u ? P : 128u;
    ws->P = P; ws->M = M;
    ws->n_pos = npos; ws->n_neg = 256u - npos;
    ws->S[0] = P; ws->S[1] = M;
    ws->kcnt[0] = npos; ws->kcnt[1] = 256u - npos;
    const double LOGU = 22.18070977791825;  // log(2^32 - 1)
    for (int d = 0; d < 2; ++d) {
      uint32_t Sd = ws->S[d];
      int R = 0;
      if (Sd > 1u) {
        R = (int)ceil(3.0 * log((double)Sd) / LOGU);
        if (R < 1) R = 1;
        if (R > 3) R = 3;
      }
      ws->R[d] = (uint32_t)R;
      // fold_in(key(42), d) = TF(key, 0, d)
      uint32_t ck0, ck1;
      { uint32_t a = 0u, b = (uint32_t)d; tf2(0u, 42u, a, b); ck0 = a; ck1 = b; }
      // split (partitionable/foldlike): newkey = TF(k,0,0), subkey = TF(k,0,1)
      for (int rr = 0; rr < 3; ++rr) {
        uint32_t s0 = 0u, s1 = 1u; tf2(ck0, ck1, s0, s1);
        ws->sub[d][rr][0] = s0; ws->sub[d][rr][1] = s1;
        uint32_t n0 = 0u, n1 = 0u; tf2(ck0, ck1, n0, n1);
        ck0 = n0; ck1 = n1;
      }
    }
  }
}

__global__ void k_passclear(WS* ws) {
  int g = blockIdx.x * blockDim.x + threadIdx.x;
  if (g < NBINS) { ws->hist[g] = 0u; ws->binslot[g] = -1; }
  if (g < MAXSLOT) ws->slotCnt[g] = 0u;
  if (g == 0) ws->nslots = 0u;
}

// 256 blocks x 1024 threads: 16 waves/CU; unroll-2 for independent threefry
// chains (the hash is a serial VALU dep-chain, ~4cy/op alone).
__global__ __launch_bounds__(1024) void k_hist(WS* ws, int d, int m) {
  int r = (int)ws->R[d] - m;
  if (r < 1) return;
  __shared__ uint32_t lh[NBINS];
  for (int i = threadIdx.x; i < NBINS; i += 1024) lh[i] = 0u;
  __syncthreads();
  uint32_t S = ws->S[d];
  uint32_t sk0 = ws->sub[d][r - 1][0], sk1 = ws->sub[d][r - 1][1];
  uint32_t stride = gridDim.x * blockDim.x;
  uint32_t j = blockIdx.x * blockDim.x + threadIdx.x;
  for (; j + stride < S; j += 2 * stride) {
    uint32_t k0 = tf_bits(sk0, sk1, j);
    uint32_t k1 = tf_bits(sk0, sk1, j + stride);
    atomicAdd(&lh[k0 >> BINSHIFT], 1u);
    atomicAdd(&lh[k1 >> BINSHIFT], 1u);
  }
  if (j < S) {
    uint32_t k0 = tf_bits(sk0, sk1, j);
    atomicAdd(&lh[k0 >> BINSHIFT], 1u);
  }
  __syncthreads();
  for (int i = threadIdx.x; i < NBINS; i += 1024) {
    uint32_t v = lh[i];
    if (v) atomicAdd(&ws->hist[i], v);
  }
}

// Scan hist in LDS; parallel per-target binary search; CAS-based slot dedup.
__global__ __launch_bounds__(1024) void k_scanloc(WS* ws, int d, int m) {
  int r = (int)ws->R[d] - m;
  if (r < 1) return;
  __shared__ uint32_t cumS[NBINS + 1];
  __shared__ uint32_t part[1024];
  int t = threadIdx.x;
  const int E = NBINS / 1024;  // 8
  uint32_t lv[E];
  uint32_t s = 0;
  uint32_t base = (uint32_t)t * E;
#pragma unroll
  for (int e = 0; e < E; ++e) { lv[e] = ws->hist[base + e]; s += lv[e]; }
  part[t] = s;
  __syncthreads();
  for (int off = 1; off < 1024; off <<= 1) {
    uint32_t add = (t >= off) ? part[t - off] : 0u;
    __syncthreads();
    part[t] += add;
    __syncthreads();
  }
  uint32_t run = part[t] - s;
#pragma unroll
  for (int e = 0; e < E; ++e) { cumS[base + e] = run; run += lv[e]; }
  if (t == 1023) cumS[NBINS] = run;
  __syncthreads();

  uint32_t k = ws->kcnt[d];
  uint32_t lo = 0;
  int old = 0;
  if (t < (int)k) {
    uint32_t tr = ws->tgt[d][t];
    uint32_t hi = NBINS;  // invariant: cumS[lo] <= tr < cumS[hi]
    while (hi - lo > 1u) {
      uint32_t mid = (lo + hi) >> 1;
      if (cumS[mid] <= tr) lo = mid; else hi = mid;
    }
    ws->tlocal[t] = tr - cumS[lo];
    // phase 1: claim the bin (marker = 0x10000+t, never collides with slot id)
    old = atomicCAS(&ws->binslot[lo], -1, (int)(0x10000u + (uint32_t)t));
  }
  __syncthreads();
  // phase 2: winners allocate dense slot ids and overwrite the marker
  if (t < (int)k && old == -1) {
    uint32_t slot = atomicAdd(&ws->nslots, 1u);
    ws->binslot[lo] = (int)slot;
  }
  __syncthreads();
  // phase 3: everyone reads the final slot id
  if (t < (int)k) ws->tslot[t] = ws->binslot[lo];
}

// binslot in LDS (no dependent global load); hits buffered in LDS; per-slot
// range reservation (1 global atomic per (block,slot)) + grouped writes.
__global__ __launch_bounds__(1024) void k_gather(WS* ws, int d, int m) {
  int r = (int)ws->R[d] - m;
  if (r < 1) return;
  __shared__ int bs[NBINS];            // 32KB
  __shared__ uint32_t hk[HCAP];        // 8KB
  __shared__ uint32_t hj[HCAP];        // 8KB
  __shared__ uint32_t scnt[MAXSLOT];
  __shared__ uint32_t sbase[MAXSLOT];
  __shared__ uint32_t scur[MAXSLOT];
  __shared__ uint32_t hcnt;
  int t = threadIdx.x;
  for (int i = t; i < NBINS; i += 1024) bs[i] = ws->binslot[i];
  if (t < MAXSLOT) scnt[t] = 0u;
  if (t == 0) hcnt = 0u;
  __syncthreads();
  uint32_t S = ws->S[d];
  uint32_t sk0 = ws->sub[d][r - 1][0], sk1 = ws->sub[d][r - 1][1];
  uint32_t stride = gridDim.x * blockDim.x;
  for (uint32_t j = blockIdx.x * blockDim.x + t; j < S; j += stride) {
    uint32_t kk = tf_bits(sk0, sk1, j);
    int sl = bs[kk >> BINSHIFT];
    if (sl >= 0) {
      uint32_t h = atomicAdd(&hcnt, 1u);
      if (h < HCAP) {
        hk[h] = kk; hj[h] = j;
        atomicAdd(&scnt[sl], 1u);
      } else {  // overflow fallback (statistically never: mean ~600, cap 2048)
        uint32_t idx = atomicAdd(&ws->slotCnt[sl], 1u);
        if (idx < SLOTCAP) ws->slotBuf[sl][idx] = ((ull)kk << 24) | (ull)j;
      }
    }
  }
  __syncthreads();
  // reserve global ranges, one atomic per touched slot
  if (t < MAXSLOT) {
    scur[t] = 0u;
    if (scnt[t]) sbase[t] = atomicAdd(&ws->slotCnt[t], scnt[t]);
  }
  __syncthreads();
  uint32_t n = hcnt < (uint32_t)HCAP ? hcnt : (uint32_t)HCAP;
  for (uint32_t h = t; h < n; h += 1024) {
    uint32_t kk = hk[h], j = hj[h];
    int sl = bs[kk >> BINSHIFT];
    uint32_t idx = sbase[sl] + atomicAdd(&scur[sl], 1u);
    if (idx < SLOTCAP) ws->slotBuf[sl][idx] = ((ull)kk << 24) | (ull)j;
  }
}

// Sort one needed bin in LDS (packed (key,pos) => exact stable order),
// pick the elements whose local rank matches each target in this bin.
__global__ __launch_bounds__(256) void k_bsort(WS* ws, int d, int m) {
  int r = (int)ws->R[d] - m;
  if (r < 1) return;
  int slot = blockIdx.x;
  if (slot >= (int)ws->nslots) return;
  __shared__ ull sh[NPAD];
  uint32_t cnt = ws->slotCnt[slot];
  if (cnt > SLOTCAP) cnt = SLOTCAP;
  int n2 = 256;
  while (n2 < (int)cnt) n2 <<= 1;  // <= 4096
  for (int i = threadIdx.x; i < n2; i += 256)
    sh[i] = (i < (int)cnt) ? ws->slotBuf[slot][i] : ~0ull;
  __syncthreads();
  for (int ksz = 2; ksz <= n2; ksz <<= 1) {
    for (int jsz = ksz >> 1; jsz > 0; jsz >>= 1) {
      for (int i = threadIdx.x; i < n2; i += 256) {
        int p = i ^ jsz;
        if (p > i) {
          ull a = sh[i], b = sh[p];
          bool up = ((i & ksz) == 0);
          if (up ? (a > b) : (a < b)) { sh[i] = b; sh[p] = a; }
        }
      }
      __syncthreads();
    }
  }
  uint32_t k = ws->kcnt[d];
  for (uint32_t sId = threadIdx.x; sId < k; sId += 256) {
    if (ws->tslot[sId] == slot) {
      ull v = sh[ws->tlocal[sId]];
      ws->tgt[d][sId] = (uint32_t)(v & 0xFFFFFFull);
    }
  }
}

__device__ __forceinline__ float sl1(float dd) {
  float ad = fabsf(dd);
  return (ad < 1.0f) ? 0.5f * dd * dd : ad - 0.5f;
}

__global__ __launch_bounds__(256) void k_loss(WS* ws,
                                              const float* __restrict__ reg,
                                              const float* __restrict__ obj,
                                              const float4* __restrict__ tgtb,
                                              const float4* __restrict__ anch,
                                              float* out) {
  int s = threadIdx.x;
  uint32_t npos = ws->n_pos;
  double lr = 0.0, bc = 0.0;
  if (s < (int)npos) {
    uint32_t v = ws->tgt[0][s];
    uint32_t pa = ws->T[v];
    uint32_t i = pa >> 6, j = pa & 63u;
    float4 t = tgtb[j];
    float tcx = (t.x + t.z) * 0.5f, tcy = (t.y + t.w) * 0.5f;
    float tw = t.z - t.x, th = t.w - t.y;
    float4 a = anch[i];
    float r0 = (tcx - a.x) / a.z;
    float r1 = (tcy - a.y) / a.w;
    float r2 = logf(tw / a.z);
    float r3 = logf(th / a.w);
    lr = (double)sl1(reg[i * 4 + 0] - r0) + (double)sl1(reg[i * 4 + 1] - r1) +
         (double)sl1(reg[i * 4 + 2] - r2) + (double)sl1(reg[i * 4 + 3] - r3);
    float x = obj[i];
    bc = (double)(fmaxf(x, 0.0f) - x + log1pf(expf(-fabsf(x))));
  } else {
    uint32_t e = ws->tgt[1][s - (int)npos];
    uint32_t f = e;
    uint32_t P = ws->P;
    for (uint32_t q = 0; q < P; ++q) {
      if (ws->T[q] <= f) f++; else break;
    }
    uint32_t i = f >> 6;
    float x = obj[i];
    bc = (double)(fmaxf(x, 0.0f) + log1pf(expf(-fabsf(x))));
  }
  __shared__ double sA[256], sB[256];
  sA[s] = lr; sB[s] = bc;
  __syncthreads();
  for (int off = 128; off > 0; off >>= 1) {
    if (s < off) { sA[s] += sA[s + off]; sB[s] += sB[s + off]; }
    __syncthreads();
  }
  if (s == 0)
    out[0] = (float)(sA[0] * (10.0 / 2500.0) + sB[0] * (1.0 / 256.0));
}

extern "C" void kernel_launch(void* const* d_in, const int* in_sizes, int n_in,
                              void* d_out, int out_size, void* d_ws,
                              size_t ws_size, hipStream_t stream) {
  const float*  reg  = (const float*)d_in[0];
  const float*  obj  = (const float*)d_in[1];
  const float4* pred = (const float4*)d_in[2];
  const float4* tgtb = (const float4*)d_in[3];
  const float4* anch = (const float4*)d_in[4];
  float* out = (float*)d_out;
  WS* ws = (WS*)d_ws;
  (void)in_sizes; (void)n_in; (void)out_size; (void)ws_size;

  k_init<<<1, 64, 0, stream>>>(ws);
  k_iou<<<N_PRED / 256, 256, 0, stream>>>(pred, tgtb, ws);
  k_fix<<<1, 64, 0, stream>>>(ws);
  k_collect<<<1, 1024, 0, stream>>>(ws);
  for (int d = 0; d < 2; ++d) {
    for (int m = 0; m < 3; ++m) {
      k_passclear<<<(NBINS + 255) / 256, 256, 0, stream>>>(ws);
      k_hist<<<256, 1024, 0, stream>>>(ws, d, m);
      k_scanloc<<<1, 1024, 0, stream>>>(ws, d, m);
      k_gather<<<256, 1024, 0, stream>>>(ws, d, m);
      k_bsort<<<MAXSLOT, 256, 0, stream>>>(ws, d, m);
    }
  }
  k_loss<<<1, 256, 0, stream>>>(ws, reg, obj, tgtb, anch, out);
}

// Round 4
// 594.978 us; speedup vs baseline: 4.6805x; 1.2942x over previous
//
#include <hip/hip_runtime.h>
#include <stdint.h>

// ---------------------------------------------------------------------------
// RPN loss: IoU>0.7 matching + argmax fix + exact JAX threefry sampling
// (partitionable PRNG path) + smooth-L1 + BCE, all on device.
// R1: k_scanloc serial tail -> LDS cum + parallel search (2785->1408us).
// R2: k_gather latency fix (binslot in LDS, range reservation) (1408->770us).
// R3: k_iou was an LDS 64-bit atomicMax CAS storm (64 lanes, same address,
//     ~960 VALU instr/col/wave -> 218us). Now: wave fmax butterfly + ballot
//     argmax, 1 LDS atomic/wave/col. k_fix merged into k_collect.
// ---------------------------------------------------------------------------

#define N_PRED   131072
#define NBOXK    64
#define NM_TOT   8388608u          // N_PRED * NBOXK
#define TCAP     65536
#define NBINS    8192
#define BINSHIFT 19                // key >> 19 -> 13-bit bin
#define SLOTCAP  3072
#define MAXSLOT  192
#define NPAD     4096
#define HCAP     2048              // per-block LDS hit buffer (gather)

typedef unsigned long long ull;

struct WS {
  uint32_t P, M, n_pos, n_neg;
  uint32_t R[2];                   // shuffle rounds per chain (0=pos,1=neg)
  uint32_t S[2];                   // sizes per chain
  uint32_t kcnt[2];                // target counts per chain
  uint32_t sub[2][3][2];           // per-round subkeys
  uint32_t nslots;
  uint32_t pad_[31];
  ull      colBest[NBOXK];         // packed (iou_bits<<32)|~row
  ull      maskWords[N_PRED];      // 64 mask bits per pred row
  uint32_t T[TCAP];                // sorted flat positions of mask==true
  uint32_t tgt[2][256];            // current target ranks / positions
  uint32_t hist[NBINS];
  int32_t  binslot[NBINS];
  int32_t  tslot[256];
  uint32_t tlocal[256];
  uint32_t slotCnt[MAXSLOT];
  ull      slotBuf[MAXSLOT][SLOTCAP];
};

// Threefry-2x32-20, matches JAX reference implementation exactly.
__device__ __forceinline__ void tf2(uint32_t k0, uint32_t k1,
                                    uint32_t& x0, uint32_t& x1) {
  uint32_t ks[3] = {k0, k1, k0 ^ k1 ^ 0x1BD11BDAu};
  const uint32_t R0[4] = {13u, 15u, 26u, 6u};
  const uint32_t R1[4] = {17u, 29u, 16u, 24u};
  x0 += ks[0]; x1 += ks[1];
#pragma unroll
  for (int i = 0; i < 5; ++i) {
    const uint32_t* rr = (i & 1) ? R1 : R0;
#pragma unroll
    for (int j = 0; j < 4; ++j) {
      x0 += x1;
      x1 = (x1 << rr[j]) | (x1 >> (32u - rr[j]));
      x1 ^= x0;
    }
    x0 += ks[(i + 1) % 3];
    x1 += ks[(i + 2) % 3] + (uint32_t)(i + 1);
  }
}

// partitionable random_bits for 32-bit: xor of the two outputs, counter = pos
__device__ __forceinline__ uint32_t tf_bits(uint32_t k0, uint32_t k1, uint32_t p) {
  uint32_t a = 0u, b = p;
  tf2(k0, k1, a, b);
  return a ^ b;
}

__global__ void k_init(WS* ws) {
  int t = threadIdx.x;
  if (t < NBOXK) ws->colBest[t] = 0ull;
}

// IoU mask + per-column argmax via wave butterfly + ballot (no atomic storm).
// Bit-exact f32 (no FMA contraction). iou is never NaN (union > 0 always).
__global__ __launch_bounds__(256) void k_iou(const float4* __restrict__ pred,
                                             const float4* __restrict__ tgtb,
                                             WS* ws) {
  __shared__ float4 tb[NBOXK];
  __shared__ float ta[NBOXK];
  __shared__ ull cb[NBOXK];
  int tid = threadIdx.x;
  if (tid < NBOXK) {
    float4 b = tgtb[tid];
    tb[tid] = b;
    ta[tid] = __fmul_rn(__fsub_rn(b.z, b.x), __fsub_rn(b.w, b.y));
    cb[tid] = 0ull;
  }
  __syncthreads();
  int i = blockIdx.x * blockDim.x + tid;
  float4 p = pred[i];
  float pa = __fmul_rn(__fsub_rn(p.z, p.x), __fsub_rn(p.w, p.y));
  ull word = 0ull;
  int lane = tid & 63;
  uint32_t wavebase = (uint32_t)(blockIdx.x * blockDim.x) + (uint32_t)(tid & ~63);
  for (int c = 0; c < NBOXK; ++c) {
    float4 t = tb[c];
    float ltx = fmaxf(p.x, t.x), lty = fmaxf(p.y, t.y);
    float rbx = fminf(p.z, t.z), rby = fminf(p.w, t.w);
    float wx = fmaxf(__fsub_rn(rbx, ltx), 0.0f);
    float wy = fmaxf(__fsub_rn(rby, lty), 0.0f);
    float inter = __fmul_rn(wx, wy);
    float uni = __fsub_rn(__fadd_rn(pa, ta[c]), inter);
    float iou = __fdiv_rn(inter, uni);
    if (iou > 0.7f) word |= (1ull << c);
    // wave-max of iou (all lanes converge to max)
    float wm = iou;
#pragma unroll
    for (int off = 32; off > 0; off >>= 1)
      wm = fmaxf(wm, __shfl_xor(wm, off, 64));
    // lowest lane holding the max == smallest row index (argmax tiebreak)
    ull bal = __ballot(iou == wm);
    if (lane == 0) {
      uint32_t row = wavebase + (uint32_t)(__ffsll((long long)bal) - 1);
      ull pk = ((ull)__float_as_uint(wm) << 32) | (ull)(~row);
      atomicMax(&cb[c], pk);   // 4 waves -> 4-way contention only
    }
  }
  ws->maskWords[i] = word;
  __syncthreads();
  if (tid < NBOXK) atomicMax(&ws->colBest[tid], cb[tid]);
}

// Ordered collect of true positions + argmax fixup (ex-k_fix) + PRNG setup.
__global__ __launch_bounds__(1024) void k_collect(WS* ws) {
  __shared__ uint32_t part[1024];
  int t = threadIdx.x;
  // --- merged k_fix: need[c] = column max <= 0.7 -> set bit at argmax row ---
  if (t < NBOXK) {
    ull pk = ws->colBest[t];
    float best = __uint_as_float((uint32_t)(pk >> 32));
    if (!(best > 0.7f)) {
      uint32_t row = ~(uint32_t)(pk & 0xFFFFFFFFu);
      atomicOr(&ws->maskWords[row], 1ull << t);
    }
  }
  __syncthreads();
  // --- ordered collect ---
  const int ROWS = N_PRED / 1024;  // 128
  uint32_t base = (uint32_t)t * ROWS;
  uint32_t c = 0;
  for (int r = 0; r < ROWS; ++r)
    c += (uint32_t)__popcll(ws->maskWords[base + r]);
  part[t] = c;
  __syncthreads();
  for (int off = 1; off < 1024; off <<= 1) {
    uint32_t add = (t >= off) ? part[t - off] : 0u;
    __syncthreads();
    part[t] += add;
    __syncthreads();
  }
  uint32_t off0 = part[t] - c;
  uint32_t total = part[1023];
  for (int r = 0; r < ROWS; ++r) {
    ull w = ws->maskWords[base + r];
    while (w) {
      int bit = __ffsll((long long)w) - 1;
      w &= (w - 1);
      if (off0 < TCAP) ws->T[off0] = ((base + r) << 6) | (uint32_t)bit;
      off0++;
    }
  }
  if (t < 256) { ws->tgt[0][t] = (uint32_t)t; ws->tgt[1][t] = (uint32_t)t; }
  if (t == 0) {
    uint32_t P = total < (uint32_t)TCAP ? total : (uint32_t)TCAP;
    uint32_t M = NM_TOT - P;
    uint32_t npos = P < 128u ? P : 128u;
    ws->P = P; ws->M = M;
    ws->n_pos = npos; ws->n_neg = 256u - npos;
    ws->S[0] = P; ws->S[1] = M;
    ws->kcnt[0] = npos; ws->kcnt[1] = 256u - npos;
    const double LOGU = 22.18070977791825;  // log(2^32 - 1)
    for (int d = 0; d < 2; ++d) {
      uint32_t Sd = ws->S[d];
      int R = 0;
      if (Sd > 1u) {
        R = (int)ceil(3.0 * log((double)Sd) / LOGU);
        if (R < 1) R = 1;
        if (R > 3) R = 3;
      }
      ws->R[d] = (uint32_t)R;
      // fold_in(key(42), d) = TF(key, 0, d)
      uint32_t ck0, ck1;
      { uint32_t a = 0u, b = (uint32_t)d; tf2(0u, 42u, a, b); ck0 = a; ck1 = b; }
      // split (partitionable/foldlike): newkey = TF(k,0,0), subkey = TF(k,0,1)
      for (int rr = 0; rr < 3; ++rr) {
        uint32_t s0 = 0u, s1 = 1u; tf2(ck0, ck1, s0, s1);
        ws->sub[d][rr][0] = s0; ws->sub[d][rr][1] = s1;
        uint32_t n0 = 0u, n1 = 0u; tf2(ck0, ck1, n0, n1);
        ck0 = n0; ck1 = n1;
      }
    }
  }
}

__global__ void k_passclear(WS* ws) {
  int g = blockIdx.x * blockDim.x + threadIdx.x;
  if (g < NBINS) { ws->hist[g] = 0u; ws->binslot[g] = -1; }
  if (g < MAXSLOT) ws->slotCnt[g] = 0u;
  if (g == 0) ws->nslots = 0u;
}

// 256 blocks x 1024 threads: 16 waves/CU; unroll-2 for independent threefry
// chains (the hash is a serial VALU dep-chain).
__global__ __launch_bounds__(1024) void k_hist(WS* ws, int d, int m) {
  int r = (int)ws->R[d] - m;
  if (r < 1) return;
  __shared__ uint32_t lh[NBINS];
  for (int i = threadIdx.x; i < NBINS; i += 1024) lh[i] = 0u;
  __syncthreads();
  uint32_t S = ws->S[d];
  uint32_t sk0 = ws->sub[d][r - 1][0], sk1 = ws->sub[d][r - 1][1];
  uint32_t stride = gridDim.x * blockDim.x;
  uint32_t j = blockIdx.x * blockDim.x + threadIdx.x;
  for (; j + stride < S; j += 2 * stride) {
    uint32_t k0 = tf_bits(sk0, sk1, j);
    uint32_t k1 = tf_bits(sk0, sk1, j + stride);
    atomicAdd(&lh[k0 >> BINSHIFT], 1u);
    atomicAdd(&lh[k1 >> BINSHIFT], 1u);
  }
  if (j < S) {
    uint32_t k0 = tf_bits(sk0, sk1, j);
    atomicAdd(&lh[k0 >> BINSHIFT], 1u);
  }
  __syncthreads();
  for (int i = threadIdx.x; i < NBINS; i += 1024) {
    uint32_t v = lh[i];
    if (v) atomicAdd(&ws->hist[i], v);
  }
}

// Scan hist in LDS; parallel per-target binary search; CAS-based slot dedup.
__global__ __launch_bounds__(1024) void k_scanloc(WS* ws, int d, int m) {
  int r = (int)ws->R[d] - m;
  if (r < 1) return;
  __shared__ uint32_t cumS[NBINS + 1];
  __shared__ uint32_t part[1024];
  int t = threadIdx.x;
  const int E = NBINS / 1024;  // 8
  uint32_t lv[E];
  uint32_t s = 0;
  uint32_t base = (uint32_t)t * E;
#pragma unroll
  for (int e = 0; e < E; ++e) { lv[e] = ws->hist[base + e]; s += lv[e]; }
  part[t] = s;
  __syncthreads();
  for (int off = 1; off < 1024; off <<= 1) {
    uint32_t add = (t >= off) ? part[t - off] : 0u;
    __syncthreads();
    part[t] += add;
    __syncthreads();
  }
  uint32_t run = part[t] - s;
#pragma unroll
  for (int e = 0; e < E; ++e) { cumS[base + e] = run; run += lv[e]; }
  if (t == 1023) cumS[NBINS] = run;
  __syncthreads();

  uint32_t k = ws->kcnt[d];
  uint32_t lo = 0;
  int old = 0;
  if (t < (int)k) {
    uint32_t tr = ws->tgt[d][t];
    uint32_t hi = NBINS;  // invariant: cumS[lo] <= tr < cumS[hi]
    while (hi - lo > 1u) {
      uint32_t mid = (lo + hi) >> 1;
      if (cumS[mid] <= tr) lo = mid; else hi = mid;
    }
    ws->tlocal[t] = tr - cumS[lo];
    // phase 1: claim the bin (marker = 0x10000+t, never collides with slot id)
    old = atomicCAS(&ws->binslot[lo], -1, (int)(0x10000u + (uint32_t)t));
  }
  __syncthreads();
  // phase 2: winners allocate dense slot ids and overwrite the marker
  if (t < (int)k && old == -1) {
    uint32_t slot = atomicAdd(&ws->nslots, 1u);
    ws->binslot[lo] = (int)slot;
  }
  __syncthreads();
  // phase 3: everyone reads the final slot id
  if (t < (int)k) ws->tslot[t] = ws->binslot[lo];
}

// binslot in LDS (no dependent global load); hits buffered in LDS; per-slot
// range reservation (1 global atomic per (block,slot)) + grouped writes.
__global__ __launch_bounds__(1024) void k_gather(WS* ws, int d, int m) {
  int r = (int)ws->R[d] - m;
  if (r < 1) return;
  __shared__ int bs[NBINS];            // 32KB
  __shared__ uint32_t hk[HCAP];        // 8KB
  __shared__ uint32_t hj[HCAP];        // 8KB
  __shared__ uint32_t scnt[MAXSLOT];
  __shared__ uint32_t sbase[MAXSLOT];
  __shared__ uint32_t scur[MAXSLOT];
  __shared__ uint32_t hcnt;
  int t = threadIdx.x;
  for (int i = t; i < NBINS; i += 1024) bs[i] = ws->binslot[i];
  if (t < MAXSLOT) scnt[t] = 0u;
  if (t == 0) hcnt = 0u;
  __syncthreads();
  uint32_t S = ws->S[d];
  uint32_t sk0 = ws->sub[d][r - 1][0], sk1 = ws->sub[d][r - 1][1];
  uint32_t stride = gridDim.x * blockDim.x;
  for (uint32_t j = blockIdx.x * blockDim.x + t; j < S; j += stride) {
    uint32_t kk = tf_bits(sk0, sk1, j);
    int sl = bs[kk >> BINSHIFT];
    if (sl >= 0) {
      uint32_t h = atomicAdd(&hcnt, 1u);
      if (h < HCAP) {
        hk[h] = kk; hj[h] = j;
        atomicAdd(&scnt[sl], 1u);
      } else {  // overflow fallback (statistically never: mean ~600, cap 2048)
        uint32_t idx = atomicAdd(&ws->slotCnt[sl], 1u);
        if (idx < SLOTCAP) ws->slotBuf[sl][idx] = ((ull)kk << 24) | (ull)j;
      }
    }
  }
  __syncthreads();
  // reserve global ranges, one atomic per touched slot
  if (t < MAXSLOT) {
    scur[t] = 0u;
    if (scnt[t]) sbase[t] = atomicAdd(&ws->slotCnt[t], scnt[t]);
  }
  __syncthreads();
  uint32_t n = hcnt < (uint32_t)HCAP ? hcnt : (uint32_t)HCAP;
  for (uint32_t h = t; h < n; h += 1024) {
    uint32_t kk = hk[h], j = hj[h];
    int sl = bs[kk >> BINSHIFT];
    uint32_t idx = sbase[sl] + atomicAdd(&scur[sl], 1u);
    if (idx < SLOTCAP) ws->slotBuf[sl][idx] = ((ull)kk << 24) | (ull)j;
  }
}

// Sort one needed bin in LDS (packed (key,pos) => exact stable order),
// pick the elements whose local rank matches each target in this bin.
__global__ __launch_bounds__(256) void k_bsort(WS* ws, int d, int m) {
  int r = (int)ws->R[d] - m;
  if (r < 1) return;
  int slot = blockIdx.x;
  if (slot >= (int)ws->nslots) return;
  __shared__ ull sh[NPAD];
  uint32_t cnt = ws->slotCnt[slot];
  if (cnt > SLOTCAP) cnt = SLOTCAP;
  int n2 = 256;
  while (n2 < (int)cnt) n2 <<= 1;  // <= 4096
  for (int i = threadIdx.x; i < n2; i += 256)
    sh[i] = (i < (int)cnt) ? ws->slotBuf[slot][i] : ~0ull;
  __syncthreads();
  for (int ksz = 2; ksz <= n2; ksz <<= 1) {
    for (int jsz = ksz >> 1; jsz > 0; jsz >>= 1) {
      for (int i = threadIdx.x; i < n2; i += 256) {
        int p = i ^ jsz;
        if (p > i) {
          ull a = sh[i], b = sh[p];
          bool up = ((i & ksz) == 0);
          if (up ? (a > b) : (a < b)) { sh[i] = b; sh[p] = a; }
        }
      }
      __syncthreads();
    }
  }
  uint32_t k = ws->kcnt[d];
  for (uint32_t sId = threadIdx.x; sId < k; sId += 256) {
    if (ws->tslot[sId] == slot) {
      ull v = sh[ws->tlocal[sId]];
      ws->tgt[d][sId] = (uint32_t)(v & 0xFFFFFFull);
    }
  }
}

__device__ __forceinline__ float sl1(float dd) {
  float ad = fabsf(dd);
  return (ad < 1.0f) ? 0.5f * dd * dd : ad - 0.5f;
}

__global__ __launch_bounds__(256) void k_loss(WS* ws,
                                              const float* __restrict__ reg,
                                              const float* __restrict__ obj,
                                              const float4* __restrict__ tgtb,
                                              const float4* __restrict__ anch,
                                              float* out) {
  int s = threadIdx.x;
  uint32_t npos = ws->n_pos;
  double lr = 0.0, bc = 0.0;
  if (s < (int)npos) {
    uint32_t v = ws->tgt[0][s];
    uint32_t pa = ws->T[v];
    uint32_t i = pa >> 6, j = pa & 63u;
    float4 t = tgtb[j];
    float tcx = (t.x + t.z) * 0.5f, tcy = (t.y + t.w) * 0.5f;
    float tw = t.z - t.x, th = t.w - t.y;
    float4 a = anch[i];
    float r0 = (tcx - a.x) / a.z;
    float r1 = (tcy - a.y) / a.w;
    float r2 = logf(tw / a.z);
    float r3 = logf(th / a.w);
    lr = (double)sl1(reg[i * 4 + 0] - r0) + (double)sl1(reg[i * 4 + 1] - r1) +
         (double)sl1(reg[i * 4 + 2] - r2) + (double)sl1(reg[i * 4 + 3] - r3);
    float x = obj[i];
    bc = (double)(fmaxf(x, 0.0f) - x + log1pf(expf(-fabsf(x))));
  } else {
    uint32_t e = ws->tgt[1][s - (int)npos];
    uint32_t f = e;
    uint32_t P = ws->P;
    for (uint32_t q = 0; q < P; ++q) {
      if (ws->T[q] <= f) f++; else break;
    }
    uint32_t i = f >> 6;
    float x = obj[i];
    bc = (double)(fmaxf(x, 0.0f) + log1pf(expf(-fabsf(x))));
  }
  __shared__ double sA[256], sB[256];
  sA[s] = lr; sB[s] = bc;
  __syncthreads();
  for (int off = 128; off > 0; off >>= 1) {
    if (s < off) { sA[s] += sA[s + off]; sB[s] += sB[s + off]; }
    __syncthreads();
  }
  if (s == 0)
    out[0] = (float)(sA[0] * (10.0 / 2500.0) + sB[0] * (1.0 / 256.0));
}

extern "C" void kernel_launch(void* const* d_in, const int* in_sizes, int n_in,
                              void* d_out, int out_size, void* d_ws,
                              size_t ws_size, hipStream_t stream) {
  const float*  reg  = (const float*)d_in[0];
  const float*  obj  = (const float*)d_in[1];
  const float4* pred = (const float4*)d_in[2];
  const float4* tgtb = (const float4*)d_in[3];
  const float4* anch = (const float4*)d_in[4];
  float* out = (float*)d_out;
  WS* ws = (WS*)d_ws;
  (void)in_sizes; (void)n_in; (void)out_size; (void)ws_size;

  k_init<<<1, 64, 0, stream>>>(ws);
  k_iou<<<N_PRED / 256, 256, 0, stream>>>(pred, tgtb, ws);
  k_collect<<<1, 1024, 0, stream>>>(ws);
  for (int d = 0; d < 2; ++d) {
    for (int m = 0; m < 3; ++m) {
      k_passclear<<<(NBINS + 255) / 256, 256, 0, stream>>>(ws);
      k_hist<<<256, 1024, 0, stream>>>(ws, d, m);
      k_scanloc<<<1, 1024, 0, stream>>>(ws, d, m);
      k_gather<<<256, 1024, 0, stream>>>(ws, d, m);
      k_bsort<<<MAXSLOT, 256, 0, stream>>>(ws, d, m);
    }
  }
  k_loss<<<1, 256, 0, stream>>>(ws, reg, obj, tgtb, anch, out);
}

// Round 5
// 498.540 us; speedup vs baseline: 5.5859x; 1.1934x over previous
//
#include <hip/hip_runtime.h>
#include <stdint.h>

// ---------------------------------------------------------------------------
// RPN loss: IoU>0.7 matching + argmax fix + exact JAX threefry sampling
// (partitionable PRNG path) + smooth-L1 + BCE, all on device.
// R1: k_scanloc serial tail -> LDS cum + parallel search (2785->1408us).
// R2: k_gather latency fix (binslot in LDS, range reservation) (1408->770us).
// R3: k_iou LDS atomicMax CAS storm -> wave butterfly+ballot (770->595us).
// R4: k_collect was 1 block streaming 1MB (latency-bound single CU, 104us).
//     Split into k_cnt/k_setup/k_emit (512-block parallel). k_passclear
//     eliminated: scanloc clears slotCnt/nslots, bsort stripes hist/binslot
//     clear for the next round.
// ---------------------------------------------------------------------------

#define N_PRED   131072
#define NBOXK    64
#define NM_TOT   8388608u          // N_PRED * NBOXK
#define TCAP     65536
#define NBINS    8192
#define BINSHIFT 19                // key >> 19 -> 13-bit bin
#define SLOTCAP  3072
#define MAXSLOT  192
#define NPAD     4096
#define HCAP     2048              // per-block LDS hit buffer (gather)
#define CBLK     512               // collect blocks (256 rows each... 131072/256)

typedef unsigned long long ull;

struct WS {
  uint32_t P, M, n_pos, n_neg;
  uint32_t R[2];                   // shuffle rounds per chain (0=pos,1=neg)
  uint32_t S[2];                   // sizes per chain
  uint32_t kcnt[2];                // target counts per chain
  uint32_t sub[2][3][2];           // per-round subkeys
  uint32_t nslots;
  uint32_t pad_[31];
  ull      colBest[NBOXK];         // packed (iou_bits<<32)|~row
  ull      maskWords[N_PRED];      // 64 mask bits per pred row
  uint32_t T[TCAP];                // sorted flat positions of mask==true
  uint32_t tgt[2][256];            // current target ranks / positions
  uint32_t hist[NBINS];
  int32_t  binslot[NBINS];
  int32_t  tslot[256];
  uint32_t tlocal[256];
  uint32_t blockSum[CBLK];
  uint32_t blockBase[CBLK];
  uint32_t slotCnt[MAXSLOT];
  ull      slotBuf[MAXSLOT][SLOTCAP];
};

// Threefry-2x32-20, matches JAX reference implementation exactly.
__device__ __forceinline__ void tf2(uint32_t k0, uint32_t k1,
                                    uint32_t& x0, uint32_t& x1) {
  uint32_t ks[3] = {k0, k1, k0 ^ k1 ^ 0x1BD11BDAu};
  const uint32_t R0[4] = {13u, 15u, 26u, 6u};
  const uint32_t R1[4] = {17u, 29u, 16u, 24u};
  x0 += ks[0]; x1 += ks[1];
#pragma unroll
  for (int i = 0; i < 5; ++i) {
    const uint32_t* rr = (i & 1) ? R1 : R0;
#pragma unroll
    for (int j = 0; j < 4; ++j) {
      x0 += x1;
      x1 = (x1 << rr[j]) | (x1 >> (32u - rr[j]));
      x1 ^= x0;
    }
    x0 += ks[(i + 1) % 3];
    x1 += ks[(i + 2) % 3] + (uint32_t)(i + 1);
  }
}

// partitionable random_bits for 32-bit: xor of the two outputs, counter = pos
__device__ __forceinline__ uint32_t tf_bits(uint32_t k0, uint32_t k1, uint32_t p) {
  uint32_t a = 0u, b = p;
  tf2(k0, k1, a, b);
  return a ^ b;
}

__global__ void k_init(WS* ws) {
  int t = threadIdx.x;
  if (t < NBOXK) ws->colBest[t] = 0ull;
}

// IoU mask + per-column argmax via wave butterfly + ballot (no atomic storm).
// Bit-exact f32 (no FMA contraction). iou is never NaN (union > 0 always).
__global__ __launch_bounds__(256) void k_iou(const float4* __restrict__ pred,
                                             const float4* __restrict__ tgtb,
                                             WS* ws) {
  __shared__ float4 tb[NBOXK];
  __shared__ float ta[NBOXK];
  __shared__ ull cb[NBOXK];
  int tid = threadIdx.x;
  if (tid < NBOXK) {
    float4 b = tgtb[tid];
    tb[tid] = b;
    ta[tid] = __fmul_rn(__fsub_rn(b.z, b.x), __fsub_rn(b.w, b.y));
    cb[tid] = 0ull;
  }
  __syncthreads();
  int i = blockIdx.x * blockDim.x + tid;
  float4 p = pred[i];
  float pa = __fmul_rn(__fsub_rn(p.z, p.x), __fsub_rn(p.w, p.y));
  ull word = 0ull;
  int lane = tid & 63;
  uint32_t wavebase = (uint32_t)(blockIdx.x * blockDim.x) + (uint32_t)(tid & ~63);
  for (int c = 0; c < NBOXK; ++c) {
    float4 t = tb[c];
    float ltx = fmaxf(p.x, t.x), lty = fmaxf(p.y, t.y);
    float rbx = fminf(p.z, t.z), rby = fminf(p.w, t.w);
    float wx = fmaxf(__fsub_rn(rbx, ltx), 0.0f);
    float wy = fmaxf(__fsub_rn(rby, lty), 0.0f);
    float inter = __fmul_rn(wx, wy);
    float uni = __fsub_rn(__fadd_rn(pa, ta[c]), inter);
    float iou = __fdiv_rn(inter, uni);
    if (iou > 0.7f) word |= (1ull << c);
    float wm = iou;
#pragma unroll
    for (int off = 32; off > 0; off >>= 1)
      wm = fmaxf(wm, __shfl_xor(wm, off, 64));
    ull bal = __ballot(iou == wm);
    if (lane == 0) {
      uint32_t row = wavebase + (uint32_t)(__ffsll((long long)bal) - 1);
      ull pk = ((ull)__float_as_uint(wm) << 32) | (ull)(~row);
      atomicMax(&cb[c], pk);   // 4 waves -> 4-way contention only
    }
  }
  ws->maskWords[i] = word;
  __syncthreads();
  if (tid < NBOXK) atomicMax(&ws->colBest[tid], cb[tid]);
}

// need[c] = column max <= 0.7 -> set bit at first-argmax row (idempotent)
__global__ void k_fix(WS* ws) {
  int c = threadIdx.x;
  if (c < NBOXK) {
    ull pk = ws->colBest[c];
    float best = __uint_as_float((uint32_t)(pk >> 32));
    if (!(best > 0.7f)) {
      uint32_t row = ~(uint32_t)(pk & 0xFFFFFFFFu);
      atomicOr(&ws->maskWords[row], 1ull << c);
    }
  }
}

// Per-block popcount of mask rows -> blockSum.
__global__ __launch_bounds__(256) void k_cnt(WS* ws) {
  int t = threadIdx.x;
  int row = blockIdx.x * 256 + t;
  uint32_t c = (uint32_t)__popcll(ws->maskWords[row]);
  __shared__ uint32_t sm[256];
  sm[t] = c;
  __syncthreads();
  for (int off = 128; off > 0; off >>= 1) {
    if (t < off) sm[t] += sm[t + off];
    __syncthreads();
  }
  if (t == 0) ws->blockSum[blockIdx.x] = sm[0];
}

// Scan block sums + scalar/PRNG setup + initial hist/binslot clear.
__global__ __launch_bounds__(512) void k_setup(WS* ws) {
  __shared__ uint32_t sm[CBLK];
  int t = threadIdx.x;
  uint32_t c = ws->blockSum[t];
  sm[t] = c;
  __syncthreads();
  for (int off = 1; off < CBLK; off <<= 1) {
    uint32_t add = (t >= off) ? sm[t - off] : 0u;
    __syncthreads();
    sm[t] += add;
    __syncthreads();
  }
  ws->blockBase[t] = sm[t] - c;
  uint32_t total = sm[CBLK - 1];
  // initial clears (first hist round reads these)
  for (int i = t; i < NBINS; i += CBLK) { ws->hist[i] = 0u; ws->binslot[i] = -1; }
  if (t < MAXSLOT) ws->slotCnt[t] = 0u;
  if (t < 256) { ws->tgt[0][t] = (uint32_t)t; ws->tgt[1][t] = (uint32_t)t; }
  if (t == 0) {
    ws->nslots = 0u;
    uint32_t P = total < (uint32_t)TCAP ? total : (uint32_t)TCAP;
    uint32_t M = NM_TOT - P;
    uint32_t npos = P < 128u ? P : 128u;
    ws->P = P; ws->M = M;
    ws->n_pos = npos; ws->n_neg = 256u - npos;
    ws->S[0] = P; ws->S[1] = M;
    ws->kcnt[0] = npos; ws->kcnt[1] = 256u - npos;
    const double LOGU = 22.18070977791825;  // log(2^32 - 1)
    for (int d = 0; d < 2; ++d) {
      uint32_t Sd = ws->S[d];
      int R = 0;
      if (Sd > 1u) {
        R = (int)ceil(3.0 * log((double)Sd) / LOGU);
        if (R < 1) R = 1;
        if (R > 3) R = 3;
      }
      ws->R[d] = (uint32_t)R;
      // fold_in(key(42), d) = TF(key, 0, d)
      uint32_t ck0, ck1;
      { uint32_t a = 0u, b = (uint32_t)d; tf2(0u, 42u, a, b); ck0 = a; ck1 = b; }
      // split (partitionable/foldlike): newkey = TF(k,0,0), subkey = TF(k,0,1)
      for (int rr = 0; rr < 3; ++rr) {
        uint32_t s0 = 0u, s1 = 1u; tf2(ck0, ck1, s0, s1);
        ws->sub[d][rr][0] = s0; ws->sub[d][rr][1] = s1;
        uint32_t n0 = 0u, n1 = 0u; tf2(ck0, ck1, n0, n1);
        ck0 = n0; ck1 = n1;
      }
    }
  }
}

// Ordered emit of true positions (row-major, ascending bit), parallel.
__global__ __launch_bounds__(256) void k_emit(WS* ws) {
  int t = threadIdx.x;
  int row = blockIdx.x * 256 + t;
  ull w = ws->maskWords[row];
  uint32_t c = (uint32_t)__popcll(w);
  __shared__ uint32_t sm[256];
  sm[t] = c;
  __syncthreads();
  for (int off = 1; off < 256; off <<= 1) {
    uint32_t add = (t >= off) ? sm[t - off] : 0u;
    __syncthreads();
    sm[t] += add;
    __syncthreads();
  }
  uint32_t off0 = ws->blockBase[blockIdx.x] + sm[t] - c;
  while (w) {
    int bit = __ffsll((long long)w) - 1;
    w &= (w - 1);
    if (off0 < TCAP) ws->T[off0] = ((uint32_t)row << 6) | (uint32_t)bit;
    off0++;
  }
}

// 256 blocks x 1024 threads; unroll-2 independent threefry chains.
__global__ __launch_bounds__(1024) void k_hist(WS* ws, int d, int m) {
  int r = (int)ws->R[d] - m;
  if (r < 1) return;
  __shared__ uint32_t lh[NBINS];
  for (int i = threadIdx.x; i < NBINS; i += 1024) lh[i] = 0u;
  __syncthreads();
  uint32_t S = ws->S[d];
  uint32_t sk0 = ws->sub[d][r - 1][0], sk1 = ws->sub[d][r - 1][1];
  uint32_t stride = gridDim.x * blockDim.x;
  uint32_t j = blockIdx.x * blockDim.x + threadIdx.x;
  for (; j + stride < S; j += 2 * stride) {
    uint32_t k0 = tf_bits(sk0, sk1, j);
    uint32_t k1 = tf_bits(sk0, sk1, j + stride);
    atomicAdd(&lh[k0 >> BINSHIFT], 1u);
    atomicAdd(&lh[k1 >> BINSHIFT], 1u);
  }
  if (j < S) {
    uint32_t k0 = tf_bits(sk0, sk1, j);
    atomicAdd(&lh[k0 >> BINSHIFT], 1u);
  }
  __syncthreads();
  for (int i = threadIdx.x; i < NBINS; i += 1024) {
    uint32_t v = lh[i];
    if (v) atomicAdd(&ws->hist[i], v);
  }
}

// Scan hist in LDS; parallel per-target binary search; CAS-based slot dedup.
// Also clears slotCnt/nslots for this round's gather (ex-passclear).
__global__ __launch_bounds__(1024) void k_scanloc(WS* ws, int d, int m) {
  int r = (int)ws->R[d] - m;
  if (r < 1) return;
  __shared__ uint32_t cumS[NBINS + 1];
  __shared__ uint32_t part[1024];
  int t = threadIdx.x;
  if (t == 0) ws->nslots = 0u;
  if (t < MAXSLOT) ws->slotCnt[t] = 0u;
  const int E = NBINS / 1024;  // 8
  uint32_t lv[E];
  uint32_t s = 0;
  uint32_t base = (uint32_t)t * E;
#pragma unroll
  for (int e = 0; e < E; ++e) { lv[e] = ws->hist[base + e]; s += lv[e]; }
  part[t] = s;
  __syncthreads();
  for (int off = 1; off < 1024; off <<= 1) {
    uint32_t add = (t >= off) ? part[t - off] : 0u;
    __syncthreads();
    part[t] += add;
    __syncthreads();
  }
  uint32_t run = part[t] - s;
#pragma unroll
  for (int e = 0; e < E; ++e) { cumS[base + e] = run; run += lv[e]; }
  if (t == 1023) cumS[NBINS] = run;
  __syncthreads();

  uint32_t k = ws->kcnt[d];
  uint32_t lo = 0;
  int old = 0;
  if (t < (int)k) {
    uint32_t tr = ws->tgt[d][t];
    uint32_t hi = NBINS;  // invariant: cumS[lo] <= tr < cumS[hi]
    while (hi - lo > 1u) {
      uint32_t mid = (lo + hi) >> 1;
      if (cumS[mid] <= tr) lo = mid; else hi = mid;
    }
    ws->tlocal[t] = tr - cumS[lo];
    // phase 1: claim the bin (marker = 0x10000+t, never collides with slot id)
    old = atomicCAS(&ws->binslot[lo], -1, (int)(0x10000u + (uint32_t)t));
  }
  __syncthreads();
  // phase 2: winners allocate dense slot ids and overwrite the marker
  if (t < (int)k && old == -1) {
    uint32_t slot = atomicAdd(&ws->nslots, 1u);
    ws->binslot[lo] = (int)slot;
  }
  __syncthreads();
  // phase 3: everyone reads the final slot id
  if (t < (int)k) ws->tslot[t] = ws->binslot[lo];
}

// binslot in LDS (no dependent global load); hits buffered in LDS; per-slot
// range reservation (1 global atomic per (block,slot)) + grouped writes.
__global__ __launch_bounds__(1024) void k_gather(WS* ws, int d, int m) {
  int r = (int)ws->R[d] - m;
  if (r < 1) return;
  __shared__ int bs[NBINS];            // 32KB
  __shared__ uint32_t hk[HCAP];        // 8KB
  __shared__ uint32_t hj[HCAP];        // 8KB
  __shared__ uint32_t scnt[MAXSLOT];
  __shared__ uint32_t sbase[MAXSLOT];
  __shared__ uint32_t scur[MAXSLOT];
  __shared__ uint32_t hcnt;
  int t = threadIdx.x;
  for (int i = t; i < NBINS; i += 1024) bs[i] = ws->binslot[i];
  if (t < MAXSLOT) scnt[t] = 0u;
  if (t == 0) hcnt = 0u;
  __syncthreads();
  uint32_t S = ws->S[d];
  uint32_t sk0 = ws->sub[d][r - 1][0], sk1 = ws->sub[d][r - 1][1];
  uint32_t stride = gridDim.x * blockDim.x;
  for (uint32_t j = blockIdx.x * blockDim.x + t; j < S; j += stride) {
    uint32_t kk = tf_bits(sk0, sk1, j);
    int sl = bs[kk >> BINSHIFT];
    if (sl >= 0) {
      uint32_t h = atomicAdd(&hcnt, 1u);
      if (h < HCAP) {
        hk[h] = kk; hj[h] = j;
        atomicAdd(&scnt[sl], 1u);
      } else {  // overflow fallback (statistically never)
        uint32_t idx = atomicAdd(&ws->slotCnt[sl], 1u);
        if (idx < SLOTCAP) ws->slotBuf[sl][idx] = ((ull)kk << 24) | (ull)j;
      }
    }
  }
  __syncthreads();
  if (t < MAXSLOT) {
    scur[t] = 0u;
    if (scnt[t]) sbase[t] = atomicAdd(&ws->slotCnt[t], scnt[t]);
  }
  __syncthreads();
  uint32_t n = hcnt < (uint32_t)HCAP ? hcnt : (uint32_t)HCAP;
  for (uint32_t h = t; h < n; h += 1024) {
    uint32_t kk = hk[h], j = hj[h];
    int sl = bs[kk >> BINSHIFT];
    uint32_t idx = sbase[sl] + atomicAdd(&scur[sl], 1u);
    if (idx < SLOTCAP) ws->slotBuf[sl][idx] = ((ull)kk << 24) | (ull)j;
  }
}

// Sort one needed bin in LDS; pick elements at target local ranks.
// Also stripes the hist/binslot clear for the NEXT round (ex-passclear);
// neither array is read again this round.
__global__ __launch_bounds__(256) void k_bsort(WS* ws, int d, int m) {
  int r = (int)ws->R[d] - m;
  if (r < 1) return;
  for (int i = blockIdx.x * 256 + threadIdx.x; i < NBINS; i += MAXSLOT * 256) {
    ws->hist[i] = 0u;
    ws->binslot[i] = -1;
  }
  int slot = blockIdx.x;
  if (slot >= (int)ws->nslots) return;
  __shared__ ull sh[NPAD];
  uint32_t cnt = ws->slotCnt[slot];
  if (cnt > SLOTCAP) cnt = SLOTCAP;
  int n2 = 256;
  while (n2 < (int)cnt) n2 <<= 1;  // <= 4096
  for (int i = threadIdx.x; i < n2; i += 256)
    sh[i] = (i < (int)cnt) ? ws->slotBuf[slot][i] : ~0ull;
  __syncthreads();
  for (int ksz = 2; ksz <= n2; ksz <<= 1) {
    for (int jsz = ksz >> 1; jsz > 0; jsz >>= 1) {
      for (int i = threadIdx.x; i < n2; i += 256) {
        int p = i ^ jsz;
        if (p > i) {
          ull a = sh[i], b = sh[p];
          bool up = ((i & ksz) == 0);
          if (up ? (a > b) : (a < b)) { sh[i] = b; sh[p] = a; }
        }
      }
      __syncthreads();
    }
  }
  uint32_t k = ws->kcnt[d];
  for (uint32_t sId = threadIdx.x; sId < k; sId += 256) {
    if (ws->tslot[sId] == slot) {
      ull v = sh[ws->tlocal[sId]];
      ws->tgt[d][sId] = (uint32_t)(v & 0xFFFFFFull);
    }
  }
}

__device__ __forceinline__ float sl1(float dd) {
  float ad = fabsf(dd);
  return (ad < 1.0f) ? 0.5f * dd * dd : ad - 0.5f;
}

__global__ __launch_bounds__(256) void k_loss(WS* ws,
                                              const float* __restrict__ reg,
                                              const float* __restrict__ obj,
                                              const float4* __restrict__ tgtb,
                                              const float4* __restrict__ anch,
                                              float* out) {
  int s = threadIdx.x;
  uint32_t npos = ws->n_pos;
  double lr = 0.0, bc = 0.0;
  if (s < (int)npos) {
    uint32_t v = ws->tgt[0][s];
    uint32_t pa = ws->T[v];
    uint32_t i = pa >> 6, j = pa & 63u;
    float4 t = tgtb[j];
    float tcx = (t.x + t.z) * 0.5f, tcy = (t.y + t.w) * 0.5f;
    float tw = t.z - t.x, th = t.w - t.y;
    float4 a = anch[i];
    float r0 = (tcx - a.x) / a.z;
    float r1 = (tcy - a.y) / a.w;
    float r2 = logf(tw / a.z);
    float r3 = logf(th / a.w);
    lr = (double)sl1(reg[i * 4 + 0] - r0) + (double)sl1(reg[i * 4 + 1] - r1) +
         (double)sl1(reg[i * 4 + 2] - r2) + (double)sl1(reg[i * 4 + 3] - r3);
    float x = obj[i];
    bc = (double)(fmaxf(x, 0.0f) - x + log1pf(expf(-fabsf(x))));
  } else {
    uint32_t e = ws->tgt[1][s - (int)npos];
    uint32_t f = e;
    uint32_t P = ws->P;
    for (uint32_t q = 0; q < P; ++q) {
      if (ws->T[q] <= f) f++; else break;
    }
    uint32_t i = f >> 6;
    float x = obj[i];
    bc = (double)(fmaxf(x, 0.0f) + log1pf(expf(-fabsf(x))));
  }
  __shared__ double sA[256], sB[256];
  sA[s] = lr; sB[s] = bc;
  __syncthreads();
  for (int off = 128; off > 0; off >>= 1) {
    if (s < off) { sA[s] += sA[s + off]; sB[s] += sB[s + off]; }
    __syncthreads();
  }
  if (s == 0)
    out[0] = (float)(sA[0] * (10.0 / 2500.0) + sB[0] * (1.0 / 256.0));
}

extern "C" void kernel_launch(void* const* d_in, const int* in_sizes, int n_in,
                              void* d_out, int out_size, void* d_ws,
                              size_t ws_size, hipStream_t stream) {
  const float*  reg  = (const float*)d_in[0];
  const float*  obj  = (const float*)d_in[1];
  const float4* pred = (const float4*)d_in[2];
  const float4* tgtb = (const float4*)d_in[3];
  const float4* anch = (const float4*)d_in[4];
  float* out = (float*)d_out;
  WS* ws = (WS*)d_ws;
  (void)in_sizes; (void)n_in; (void)out_size; (void)ws_size;

  k_init<<<1, 64, 0, stream>>>(ws);
  k_iou<<<N_PRED / 256, 256, 0, stream>>>(pred, tgtb, ws);
  k_fix<<<1, 64, 0, stream>>>(ws);
  k_cnt<<<CBLK, 256, 0, stream>>>(ws);
  k_setup<<<1, 512, 0, stream>>>(ws);
  k_emit<<<CBLK, 256, 0, stream>>>(ws);
  for (int d = 0; d < 2; ++d) {
    for (int m = 0; m < 3; ++m) {
      k_hist<<<256, 1024, 0, stream>>>(ws, d, m);
      k_scanloc<<<1, 1024, 0, stream>>>(ws, d, m);
      k_gather<<<256, 1024, 0, stream>>>(ws, d, m);
      k_bsort<<<MAXSLOT, 256, 0, stream>>>(ws, d, m);
    }
  }
  k_loss<<<1, 256, 0, stream>>>(ws, reg, obj, tgtb, anch, out);
}